// Round 10
// baseline (506.381 us; speedup 1.0000x reference)
//
#include <hip/hip_runtime.h>
#include <stdint.h>

#define DD   1024
#define GNUM 64

typedef __attribute__((ext_vector_type(8))) short short8;
typedef __attribute__((ext_vector_type(4))) float f32x4;

__device__ __forceinline__ ushort f2bf(float f) {
    unsigned u = __float_as_uint(f);
    u += 0x7FFFu + ((u >> 16) & 1u);   // RNE
    return (ushort)(u >> 16);
}
__device__ __forceinline__ float bf2f(ushort h) {
    return __uint_as_float(((unsigned)h) << 16);
}

__device__ __forceinline__ void load_lds16(const void* g, void* l) {
    __builtin_amdgcn_global_load_lds(
        (const __attribute__((address_space(1))) unsigned*)(uintptr_t)g,
        (__attribute__((address_space(3))) unsigned*)(uint32_t)(uintptr_t)l,
        16, 0, 0);
}

__device__ __forceinline__ int lbound(const int* a, int n, int v) {
    int lo = 0, hi = n;
    while (lo < hi) { int m = (lo + hi) >> 1; if (a[m] < v) lo = m + 1; else hi = m; }
    return lo;
}

// ---------------------------------------------------------------------------
// CSR build (by dst) + src-compaction flags.
// ---------------------------------------------------------------------------
__global__ __launch_bounds__(256) void zero_kernel(int* __restrict__ p, int n) {
    int i = blockIdx.x * 256 + threadIdx.x;
    if (i < n) p[i] = 0;
}

__global__ __launch_bounds__(256) void degflag_kernel(
    const int* __restrict__ ei, int* __restrict__ deg,
    int* __restrict__ flag, int E)
{
    int e = blockIdx.x * 256 + threadIdx.x;
    if (e < E) {
        atomicAdd(&deg[ei[E + e]], 1);
        flag[ei[e]] = 1;      // benign race, same value -> deterministic
    }
}

// ---- 3-phase hierarchical dual scan (deg, flag), all-int => deterministic --
__global__ __launch_bounds__(256) void scanA_kernel(
    const int* __restrict__ deg, const int* __restrict__ flag,
    int* __restrict__ ld, int* __restrict__ lf,
    int* __restrict__ bd, int* __restrict__ bf)
{
    __shared__ int sd[256], sf[256];
    const int b = blockIdx.x, t = threadIdx.x;
    const int i = b * 256 + t;
    const int d = deg[i], f = flag[i];
    sd[t] = d; sf[t] = f;
    __syncthreads();
    for (int ofs = 1; ofs < 256; ofs <<= 1) {
        int vd = (t >= ofs) ? sd[t - ofs] : 0;
        int vf = (t >= ofs) ? sf[t - ofs] : 0;
        __syncthreads();
        sd[t] += vd; sf[t] += vf;
        __syncthreads();
    }
    ld[i] = sd[t] - d;     // exclusive
    lf[i] = sf[t] - f;
    if (t == 255) { bd[b] = sd[255]; bf[b] = sf[255]; }
}

__global__ __launch_bounds__(256) void scanB_kernel(
    const int* __restrict__ bd, const int* __restrict__ bf,
    int* __restrict__ od, int* __restrict__ of_, int* __restrict__ nsrc)
{
    __shared__ int sd[256], sf[256];
    const int t = threadIdx.x;
    const int d = bd[t], f = bf[t];
    sd[t] = d; sf[t] = f;
    __syncthreads();
    for (int ofs = 1; ofs < 256; ofs <<= 1) {
        int vd = (t >= ofs) ? sd[t - ofs] : 0;
        int vf = (t >= ofs) ? sf[t - ofs] : 0;
        __syncthreads();
        sd[t] += vd; sf[t] += vf;
        __syncthreads();
    }
    od[t] = sd[t] - d;
    of_[t] = sf[t] - f;
    if (t == 255) *nsrc = sf[255];
}

__global__ __launch_bounds__(256) void scanC_kernel(
    const int* __restrict__ flag, const int* __restrict__ ld,
    const int* __restrict__ lf, const int* __restrict__ od,
    const int* __restrict__ of_, int* __restrict__ rowptr,
    int* __restrict__ cursor, int* __restrict__ rank,
    int* __restrict__ perm, int N, int E)
{
    const int b = blockIdx.x, t = threadIdx.x;
    const int i = b * 256 + t;
    const int rd = od[b] + ld[i];
    rowptr[i] = rd;
    cursor[i] = rd;
    const int rf = of_[b] + lf[i];
    rank[i] = rf;
    if (flag[i]) perm[rf] = i;
    if (i == N - 1) rowptr[N] = E;
}

// colb stores the COMPACTED src index (rank[src])
__global__ __launch_bounds__(256) void scatter_kernel(
    const int* __restrict__ ei, int* __restrict__ cursor,
    const int* __restrict__ rank, int* __restrict__ col, int E)
{
    int e = blockIdx.x * 256 + threadIdx.x;
    if (e < E) {
        int d = ei[E + e];
        int pos = atomicAdd(&cursor[d], 1);
        col[pos] = rank[ei[e]];
    }
}

// ---------------------------------------------------------------------------
// Fused x->bf16 + per-graph partial sums (all nodes, and deg>0 nodes only).
// ---------------------------------------------------------------------------
__global__ __launch_bounds__(256) void cvtmean_kernel(
    const float* __restrict__ x, const int* __restrict__ batch,
    const int* __restrict__ deg, ushort* __restrict__ xh,
    float* __restrict__ pm, float* __restrict__ pp, int N)
{
    const int b = blockIdx.x;          // 64*32
    const int g = b >> 5, sub = b & 31;
    const int d4 = threadIdx.x * 4;

    const int glo = lbound(batch, N, g);
    const int ghi = lbound(batch, N, g + 1);
    const int len = ghi - glo;
    const int s0 = glo + (len * sub) / 32;
    const int s1 = glo + (len * (sub + 1)) / 32;

    float4 sum = make_float4(0.f, 0.f, 0.f, 0.f);
    float4 sump = make_float4(0.f, 0.f, 0.f, 0.f);
    for (int r = s0; r < s1; ++r) {
        float4 v = *(const float4*)(x + (size_t)r * 1024 + d4);
        sum.x += v.x; sum.y += v.y; sum.z += v.z; sum.w += v.w;
        if (deg[r] > 0) { sump.x += v.x; sump.y += v.y; sump.z += v.z; sump.w += v.w; }
        ushort4 h = make_ushort4(f2bf(v.x), f2bf(v.y), f2bf(v.z), f2bf(v.w));
        *(ushort4*)(xh + (size_t)r * 1024 + d4) = h;
    }
    size_t o = (size_t)(g * 32 + sub) * 1024 + d4;
    *(float4*)(pm + o) = sum;
    *(float4*)(pp + o) = sump;
}

__global__ __launch_bounds__(256) void xbar2_kernel(
    const float* __restrict__ pm, const float* __restrict__ pp,
    const int* __restrict__ batch, float* __restrict__ Xbar,
    float* __restrict__ xsp, int N)
{
    int g = blockIdx.x >> 2;
    int c = ((blockIdx.x & 3) << 8) + threadIdx.x;
    float s = 0.f, sp = 0.f;
    #pragma unroll
    for (int k = 0; k < 32; ++k) {
        s  += pm[(size_t)(g * 32 + k) * 1024 + c];
        sp += pp[(size_t)(g * 32 + k) * 1024 + c];
    }
    int cnt = lbound(batch, N, g + 1) - lbound(batch, N, g);
    if (cnt < 1) cnt = 1;
    Xbar[g * 1024 + c] = s / (float)cnt;
    xsp[g * 1024 + c] = sp;
}

__global__ __launch_bounds__(256) void npos_kernel(
    const int* __restrict__ deg, const int* __restrict__ batch,
    float* __restrict__ npos, int N)
{
    __shared__ int r[256];
    int g = blockIdx.x, t = threadIdx.x;
    int glo = lbound(batch, N, g);
    int ghi = lbound(batch, N, g + 1);
    int c = 0;
    for (int i = glo + t; i < ghi; i += 256) c += (deg[i] > 0) ? 1 : 0;
    r[t] = c;
    __syncthreads();
    for (int s = 128; s > 0; s >>= 1) {
        if (t < s) r[t] += r[t + s];
        __syncthreads();
    }
    if (t == 0) npos[g] = (float)r[0];
}

// ---------------------------------------------------------------------------
// WbigT [2048][1024] bf16: V weights only (transposed, BN scale folded).
// ---------------------------------------------------------------------------
__global__ __launch_bounds__(256) void wbig_kernel(
    const float* __restrict__ W1, const float* __restrict__ W2,
    const float* __restrict__ g1, const float* __restrict__ g2,
    ushort* __restrict__ Wt)
{
    __shared__ float tile[32][33];
    const float SF = 1.0f / sqrtf(1.0f + 1e-5f);
    int k0 = blockIdx.x * 32, c0 = blockIdx.y * 32;
    int tx = threadIdx.x & 31, ty = threadIdx.x >> 5;
    int sec = c0 >> 10;
    int cl = (c0 & 1023) + tx;
    const float* W  = sec ? W2 : W1;
    const float* gv = sec ? g2 : g1;
    float sc = gv[cl] * SF;
    #pragma unroll
    for (int j = 0; j < 4; ++j) {
        int k = k0 + ty + j * 8;
        tile[ty + j * 8][tx] = W[(size_t)(k + 1024) * 1024 + cl] * sc;
    }
    __syncthreads();
    #pragma unroll
    for (int j = 0; j < 4; ++j) {
        int cc = ty + j * 8;
        Wt[(size_t)(c0 + cc) * 1024 + k0 + tx] = f2bf(tile[tx][cc]);
    }
}

__global__ __launch_bounds__(256) void wfold_kernel(
    const float* __restrict__ W0, const float* __restrict__ g0,
    const float* __restrict__ Wr, float* __restrict__ Wfold)
{
    __shared__ float r0s[256], r1s[256];
    const float SF = 1.0f / sqrtf(1.0f + 1e-5f);
    int k = blockIdx.x, t = threadIdx.x;
    float a0 = 0.f, a1 = 0.f;
    for (int c = t; c < 1024; c += 256) {
        float w = W0[(size_t)k * 1024 + c] * (g0[c] * SF);
        a0 += w * Wr[c * 2];
        a1 += w * Wr[c * 2 + 1];
    }
    r0s[t] = a0; r1s[t] = a1;
    __syncthreads();
    for (int s = 128; s > 0; s >>= 1) {
        if (t < s) { r0s[t] += r0s[t + s]; r1s[t] += r1s[t + s]; }
        __syncthreads();
    }
    if (t == 0) { Wfold[k * 2] = r0s[0]; Wfold[k * 2 + 1] = r1s[0]; }
}

__global__ __launch_bounds__(256) void wufold_kernel(
    const float* __restrict__ W1, const float* __restrict__ W2,
    const float* __restrict__ g1, const float* __restrict__ g2,
    const float* __restrict__ Wr, float* __restrict__ Wufold)
{
    __shared__ float r0s[256], r1s[256];
    const float SF = 1.0f / sqrtf(1.0f + 1e-5f);
    int k = blockIdx.x, t = threadIdx.x;
    float a0 = 0.f, a1 = 0.f;
    for (int c = t; c < 1024; c += 256) {
        float wu = (W1[(size_t)k * 1024 + c] - W1[(size_t)(k + 1024) * 1024 + c]) * (g1[c] * SF)
                 + (W2[(size_t)k * 1024 + c] - W2[(size_t)(k + 1024) * 1024 + c]) * (g2[c] * SF);
        a0 += wu * Wr[c * 2];
        a1 += wu * Wr[c * 2 + 1];
    }
    r0s[t] = a0; r1s[t] = a1;
    __syncthreads();
    for (int s = 128; s > 0; s >>= 1) {
        if (t < s) { r0s[t] += r0s[t + s]; r1s[t] += r1s[t + s]; }
        __syncthreads();
    }
    if (t == 0) { Wufold[k * 2] = r0s[0]; Wufold[k * 2 + 1] = r1s[0]; }
}

__global__ __launch_bounds__(256) void bfold_kernel(
    const float* __restrict__ b1, const float* __restrict__ g1, const float* __restrict__ be1,
    const float* __restrict__ b2, const float* __restrict__ g2, const float* __restrict__ be2,
    const float* __restrict__ Wr, float* __restrict__ bUWr)
{
    __shared__ float r0s[256], r1s[256];
    const float SF = 1.0f / sqrtf(1.0f + 1e-5f);
    int t = threadIdx.x;
    float a0 = 0.f, a1 = 0.f;
    for (int c = t; c < 1024; c += 256) {
        float bu = b1[c] * (g1[c] * SF) + be1[c] + b2[c] * (g2[c] * SF) + be2[c];
        a0 += bu * Wr[c * 2];
        a1 += bu * Wr[c * 2 + 1];
    }
    r0s[t] = a0; r1s[t] = a1;
    __syncthreads();
    for (int s = 128; s > 0; s >>= 1) {
        if (t < s) { r0s[t] += r0s[t + s]; r1s[t] += r1s[t + s]; }
        __syncthreads();
    }
    if (t == 0) { bUWr[0] = r0s[0]; bUWr[1] = r1s[0]; }
}

// ---------------------------------------------------------------------------
// 256x256-tile 8-phase bf16 GEMM over COMPACTED src rows.
// 160 KiB LDS: A triple-buffered (3x32KB, idx t%3), B double-buffered
// (2x32KB at ushort 49152, idx t&1). Iter t stages A(t+2)/B(t+2); boundary
// vmcnt(8) confirms A(t+1)/B(t+1) issued a FULL iteration earlier (4 phases
// of latency cover vs 2 with the old vmcnt(4) schedule).
// ---------------------------------------------------------------------------
__global__ __launch_bounds__(512, 1) void gemm8_kernel(
    const ushort* __restrict__ A, const ushort* __restrict__ Bt,
    const int* __restrict__ perm, const int* __restrict__ nsrc,
    ushort* __restrict__ C)
{
    __shared__ __align__(16) ushort SM[81920];   // 160 KiB
    const int tid  = threadIdx.x;
    const int w    = tid >> 6;
    const int lane = tid & 63;
    const int wr = w >> 2;
    const int wc = w & 3;

    const int bx  = blockIdx.x;
    const int cx  = bx & 7;             // XCD chunk
    const int idx = bx >> 3;            // 0..255
    const int mt  = (idx >> 3) * 8 + cx;
    const int nt  = idx & 7;
    const int m0 = mt * 256;
    const int n0 = nt * 256;

    const int nsv = *nsrc;
    if (m0 >= nsv) return;              // whole m-tile beyond compacted rows

    const int srow = lane >> 3;
    const int csw  = ((lane & 7) ^ srow) << 3;

    const int prow = w * 8 + srow;
    int pr[4];
    #pragma unroll
    for (int z = 0; z < 4; ++z) {
        int r = m0 + z * 64 + prow;
        int p_ = perm[r];
        pr[z] = (r < nsv) ? p_ : 0;
    }

    auto stA = [&](int t, int h) {
        if (t >= 16) return;
        const int c3 = t % 3;
        const ushort* s0 = A + (size_t)pr[2 * h]     * 1024 + t * 64 + csw;
        const ushort* s1 = A + (size_t)pr[2 * h + 1] * 1024 + t * 64 + csw;
        ushort* d = SM + c3 * 16384 + h * 8192 + w * 512;
        load_lds16(s0, d);
        load_lds16(s1, d + 4096);
    };
    auto stB = [&](int t, int h) {
        if (t >= 16) return;
        const int c2 = t & 1;
        const ushort* s = Bt + (size_t)(n0 + h * 128 + w * 8 + srow) * 1024 + t * 64 + csw;
        ushort* d = SM + 49152 + c2 * 16384 + h * 8192 + w * 512;
        load_lds16(s, d);
        load_lds16(s + (size_t)64 * 1024, d + 4096);
    };

    const int cbk0 = ((lane >> 4) << 4);
    const int cbx2 = (lane & 7) << 4;
    auto rdA = [&](int c3, int i, int kk) -> short8 {
        int row = i * 16 + (lane & 15);
        int cb  = (kk * 64 + cbk0) ^ cbx2;
        return *(const short8*)((const char*)SM + (c3 * 16384 + wr * 8192) * 2 + row * 128 + cb);
    };
    auto rdB = [&](int c2, int j, int kk) -> short8 {
        int row = (wc & 1) * 64 + j * 16 + (lane & 15);
        int cb  = (kk * 64 + cbk0) ^ cbx2;
        return *(const short8*)((const char*)SM + 98304 + (c2 * 16384 + (wc >> 1) * 8192) * 2 + row * 128 + cb);
    };

    f32x4 acc[8][4];
    #pragma unroll
    for (int i = 0; i < 8; ++i)
        #pragma unroll
        for (int j = 0; j < 4; ++j)
            acc[i][j] = (f32x4){0.f, 0.f, 0.f, 0.f};

    short8 afr[4][2], bfr[4][2];

    // prologue: A0,B0 first, then A1,B1; vmcnt(8) confirms A0,B0
    stA(0, 0); stA(0, 1); stB(0, 0); stB(0, 1);
    stA(1, 0); stA(1, 1); stB(1, 0); stB(1, 1);
    asm volatile("s_waitcnt vmcnt(8)" ::: "memory");
    __builtin_amdgcn_s_barrier();

    for (int t = 0; t < 16; ++t) {
        const int c3 = t % 3;
        const int c2 = t & 1;
        // P1: read A(i0-3), B(j0-1); stage A(t+2,0)
        #pragma unroll
        for (int i = 0; i < 4; ++i) { afr[i][0] = rdA(c3, i, 0); afr[i][1] = rdA(c3, i, 1); }
        #pragma unroll
        for (int j = 0; j < 2; ++j) { bfr[j][0] = rdB(c2, j, 0); bfr[j][1] = rdB(c2, j, 1); }
        stA(t + 2, 0);
        __builtin_amdgcn_s_barrier();
        __builtin_amdgcn_s_setprio(1);
        #pragma unroll
        for (int i = 0; i < 4; ++i)
            #pragma unroll
            for (int j = 0; j < 2; ++j) {
                acc[i][j] = __builtin_amdgcn_mfma_f32_16x16x32_bf16(bfr[j][0], afr[i][0], acc[i][j], 0, 0, 0);
                acc[i][j] = __builtin_amdgcn_mfma_f32_16x16x32_bf16(bfr[j][1], afr[i][1], acc[i][j], 0, 0, 0);
            }
        __builtin_amdgcn_s_setprio(0);
        __builtin_amdgcn_s_barrier();

        // P2: read B(j2-3); stage A(t+2,1)
        #pragma unroll
        for (int j = 2; j < 4; ++j) { bfr[j][0] = rdB(c2, j, 0); bfr[j][1] = rdB(c2, j, 1); }
        stA(t + 2, 1);
        __builtin_amdgcn_s_barrier();
        __builtin_amdgcn_s_setprio(1);
        #pragma unroll
        for (int i = 0; i < 4; ++i)
            #pragma unroll
            for (int j = 2; j < 4; ++j) {
                acc[i][j] = __builtin_amdgcn_mfma_f32_16x16x32_bf16(bfr[j][0], afr[i][0], acc[i][j], 0, 0, 0);
                acc[i][j] = __builtin_amdgcn_mfma_f32_16x16x32_bf16(bfr[j][1], afr[i][1], acc[i][j], 0, 0, 0);
            }
        __builtin_amdgcn_s_setprio(0);
        __builtin_amdgcn_s_barrier();

        // P3: read A(i4-7); stage B(t+2,0)
        #pragma unroll
        for (int i = 0; i < 4; ++i) { afr[i][0] = rdA(c3, i + 4, 0); afr[i][1] = rdA(c3, i + 4, 1); }
        stB(t + 2, 0);
        __builtin_amdgcn_s_barrier();
        __builtin_amdgcn_s_setprio(1);
        #pragma unroll
        for (int i = 0; i < 4; ++i)
            #pragma unroll
            for (int j = 2; j < 4; ++j) {
                acc[i + 4][j] = __builtin_amdgcn_mfma_f32_16x16x32_bf16(bfr[j][0], afr[i][0], acc[i + 4][j], 0, 0, 0);
                acc[i + 4][j] = __builtin_amdgcn_mfma_f32_16x16x32_bf16(bfr[j][1], afr[i][1], acc[i + 4][j], 0, 0, 0);
            }
        __builtin_amdgcn_s_setprio(0);
        __builtin_amdgcn_s_barrier();

        // P4: stage B(t+2,1); boundary wait
        stB(t + 2, 1);
        __builtin_amdgcn_s_barrier();
        __builtin_amdgcn_s_setprio(1);
        #pragma unroll
        for (int i = 0; i < 4; ++i)
            #pragma unroll
            for (int j = 0; j < 2; ++j) {
                acc[i + 4][j] = __builtin_amdgcn_mfma_f32_16x16x32_bf16(bfr[j][0], afr[i][0], acc[i + 4][j], 0, 0, 0);
                acc[i + 4][j] = __builtin_amdgcn_mfma_f32_16x16x32_bf16(bfr[j][1], afr[i][1], acc[i + 4][j], 0, 0, 0);
            }
        __builtin_amdgcn_s_setprio(0);
        if (t < 15) {
            if (t < 14) asm volatile("s_waitcnt vmcnt(8)" ::: "memory");
            else        asm volatile("s_waitcnt vmcnt(0)" ::: "memory");
            __builtin_amdgcn_s_barrier();
        }
    }

    // epilogue (swapped D): lane owns row ml x 4 consecutive cols nl.
    // Restage into SM[0..128K) with XOR key (ml&15)<<2 (16 bank classes).
    __syncthreads();
    {
        const int mls = wr * 128 + (lane & 15);
        const int nls = wc * 64 + ((lane >> 4) << 2);
        #pragma unroll
        for (int j = 0; j < 4; ++j) {
            const int nl = nls + j * 16;
            #pragma unroll
            for (int i = 0; i < 8; ++i) {
                const int ml = mls + i * 16;
                unsigned lo = (unsigned)f2bf(acc[i][j][0]) |
                              ((unsigned)f2bf(acc[i][j][1]) << 16);
                unsigned hi = (unsigned)f2bf(acc[i][j][2]) |
                              ((unsigned)f2bf(acc[i][j][3]) << 16);
                int u = (ml * 256 + nl) ^ ((ml & 15) << 2);
                *(uint2*)(SM + u) = make_uint2(lo, hi);
            }
        }
    }
    __syncthreads();
    #pragma unroll
    for (int p = 0; p < 32; ++p) {
        const int idx2 = p * 512 + tid;      // 16384 uint2 slots
        const int row = idx2 >> 6;
        const int cu  = (idx2 & 63) * 4;     // ushort offset
        int u = (row * 256 + cu) ^ ((row & 15) << 2);
        uint2 v = *(const uint2*)(SM + u);
        *(uint2*)(&C[(size_t)(m0 + row) * 2048 + n0 + cu]) = v;
    }
}

// ---------------------------------------------------------------------------
// Fused gather-max + pool partials over compacted V rows (2048 cols).
// ---------------------------------------------------------------------------
__global__ __launch_bounds__(256) void edgepool_kernel(
    const ushort* __restrict__ C, const int* __restrict__ rowptr,
    const int* __restrict__ colb, const int* __restrict__ batch,
    float* __restrict__ partial, int N)
{
    const int b = blockIdx.x;          // 64*16
    const int g = b >> 4, sub = b & 15;
    const int d8 = threadIdx.x * 8;

    const int glo = lbound(batch, N, g);
    const int ghi = lbound(batch, N, g + 1);
    const int len = ghi - glo;
    const int s0 = glo + (len * sub) / 16;
    const int s1 = glo + (len * (sub + 1)) / 16;

    float vsum[8];
    #pragma unroll
    for (int q = 0; q < 8; ++q) vsum[q] = 0.f;

    int lo = (s0 < s1) ? rowptr[s0] : 0;
    for (int node = s0; node < s1; ++node) {
        int hi = rowptr[node + 1];
        if (hi > lo) {
            float vmax[8];
            #pragma unroll
            for (int q = 0; q < 8; ++q) vmax[q] = -3.4e38f;
            for (int j = lo; j < hi; ++j) {
                int src = colb[j];
                short8 v = *(const short8*)(C + (size_t)src * 2048 + d8);
                #pragma unroll
                for (int q = 0; q < 8; ++q)
                    vmax[q] = fmaxf(vmax[q], bf2f((ushort)v[q]));
            }
            #pragma unroll
            for (int q = 0; q < 8; ++q) vsum[q] += vmax[q];
        }
        lo = hi;
    }
    float* p = partial + (size_t)(g * 16 + sub) * 2048 + d8;
    *(float4*)(p)     = make_float4(vsum[0], vsum[1], vsum[2], vsum[3]);
    *(float4*)(p + 4) = make_float4(vsum[4], vsum[5], vsum[6], vsum[7]);
}

__global__ __launch_bounds__(256) void poolreduce_kernel(
    const float* __restrict__ partial, const int* __restrict__ batch,
    float* __restrict__ acc, int N)
{
    int g = blockIdx.x >> 2;
    int c = ((blockIdx.x & 3) << 8) + threadIdx.x;
    float s = 0.f;
    #pragma unroll
    for (int k = 0; k < 16; ++k) {
        const float* p = partial + (size_t)(g * 16 + k) * 2048;
        s += p[c] + p[c + 1024];
    }
    int cnt = lbound(batch, N, g + 1) - lbound(batch, N, g);
    if (cnt < 1) cnt = 1;
    acc[g * 1024 + c] = s / (float)cnt;
}

__global__ __launch_bounds__(256) void final_kernel(
    const float* __restrict__ acc, const float* __restrict__ Xbar,
    const float* __restrict__ xsp, const float* __restrict__ npos,
    const float* __restrict__ Wfold, const float* __restrict__ Wufold,
    const float* __restrict__ bUWr, const float* __restrict__ Wr,
    const float* __restrict__ b0, const float* __restrict__ g0,
    const float* __restrict__ be0, const float* __restrict__ br,
    const int* __restrict__ batch, float* __restrict__ out, int N)
{
    __shared__ float r0[256], r1[256], r2[256], r3[256];
    const float SF = 1.0f / sqrtf(1.0f + 1e-5f);
    int g = blockIdx.x, t = threadIdx.x;
    float p0 = 0.f, p1 = 0.f, q0 = 0.f, q1 = 0.f;
    for (int c = t; c < 1024; c += 256) {
        float a = acc[g * 1024 + c] + b0[c] * (g0[c] * SF) + be0[c];
        p0 += a * Wr[c * 2];
        p1 += a * Wr[c * 2 + 1];
        float xb = Xbar[g * 1024 + c];
        p0 += xb * Wfold[c * 2];
        p1 += xb * Wfold[c * 2 + 1];
        float xs = xsp[g * 1024 + c];
        q0 += xs * Wufold[c * 2];
        q1 += xs * Wufold[c * 2 + 1];
    }
    r0[t] = p0; r1[t] = p1; r2[t] = q0; r3[t] = q1;
    __syncthreads();
    for (int s = 128; s > 0; s >>= 1) {
        if (t < s) {
            r0[t] += r0[t + s]; r1[t] += r1[t + s];
            r2[t] += r2[t + s]; r3[t] += r3[t + s];
        }
        __syncthreads();
    }
    if (t == 0) {
        int cnt = lbound(batch, N, g + 1) - lbound(batch, N, g);
        if (cnt < 1) cnt = 1;
        float ic = 1.0f / (float)cnt;
        out[g * 2 + 0] = r0[0] + (r2[0] + npos[g] * bUWr[0]) * ic + br[0];
        out[g * 2 + 1] = r1[0] + (r3[0] + npos[g] * bUWr[1]) * ic + br[1];
    }
}

extern "C" void kernel_launch(void* const* d_in, const int* in_sizes, int n_in,
                              void* d_out, int out_size, void* d_ws, size_t ws_size,
                              hipStream_t stream)
{
    const float* x   = (const float*)d_in[0];
    const int*   ei  = (const int*)d_in[1];
    const int* batch = (const int*)d_in[2];
    const float* W0  = (const float*)d_in[3];
    const float* b0  = (const float*)d_in[4];
    const float* g0  = (const float*)d_in[5];
    const float* be0 = (const float*)d_in[6];
    const float* W1  = (const float*)d_in[7];
    const float* b1  = (const float*)d_in[8];
    const float* g1  = (const float*)d_in[9];
    const float* be1 = (const float*)d_in[10];
    const float* W2  = (const float*)d_in[11];
    const float* b2  = (const float*)d_in[12];
    const float* g2  = (const float*)d_in[13];
    const float* be2 = (const float*)d_in[14];
    const float* Wr  = (const float*)d_in[15];
    const float* br  = (const float*)d_in[16];
    float* out = (float*)d_out;

    const int N = in_sizes[2];       // 65536
    const int E = in_sizes[1] / 2;   // 131072

    char* ws = (char*)d_ws;
    size_t off = 0;
    auto alloc = [&](size_t bytes) -> void* {
        off = (off + 255) & ~(size_t)255;
        void* p = ws + off;
        off += bytes;
        return p;
    };
    ushort*   xh      = (ushort*)alloc((size_t)N * 1024 * 2);
    ushort*   Wt      = (ushort*)alloc((size_t)2048 * 1024 * 2);
    float*    Xbar    = (float*)alloc(64 * 1024 * 4);
    float*    xsp     = (float*)alloc(64 * 1024 * 4);
    float*    accb    = (float*)alloc(64 * 1024 * 4);
    float*    Wfold   = (float*)alloc(1024 * 2 * 4);
    float*    Wufold  = (float*)alloc(1024 * 2 * 4);
    float*    bUWr    = (float*)alloc(256);
    float*    nposb   = (float*)alloc(64 * 4);
    ushort*   Cbuf    = (ushort*)alloc((size_t)N * 2048 * 2);
    float*    partial = (float*)alloc((size_t)1024 * 2048 * 4);
    float*    pm      = (float*)alloc((size_t)2048 * 1024 * 4);
    float*    pp      = (float*)alloc((size_t)2048 * 1024 * 4);
    int*      deg     = (int*)alloc((size_t)N * 4);
    int*      flag    = (int*)alloc((size_t)N * 4);
    int*      rowptr  = (int*)alloc(((size_t)N + 1) * 4);
    int*      cursor  = (int*)alloc((size_t)N * 4);
    int*      rank    = (int*)alloc((size_t)N * 4);
    int*      perm    = (int*)alloc((size_t)N * 4);
    int*      nsrc    = (int*)alloc(256);
    int*      colb    = (int*)alloc((size_t)E * 4);
    int*      ldv     = (int*)alloc((size_t)N * 4);
    int*      lfv     = (int*)alloc((size_t)N * 4);
    int*      bdv     = (int*)alloc(256 * 4);
    int*      bfv     = (int*)alloc(256 * 4);
    int*      odv     = (int*)alloc(256 * 4);
    int*      ofv     = (int*)alloc(256 * 4);
    (void)ws_size; (void)n_in; (void)out_size;

    // CSR + compaction (hierarchical 3-phase dual scan)
    zero_kernel<<<(N + 255) / 256, 256, 0, stream>>>(deg, N);
    zero_kernel<<<(N + 255) / 256, 256, 0, stream>>>(flag, N);
    degflag_kernel<<<(E + 255) / 256, 256, 0, stream>>>(ei, deg, flag, E);
    scanA_kernel<<<N / 256, 256, 0, stream>>>(deg, flag, ldv, lfv, bdv, bfv);
    scanB_kernel<<<1, 256, 0, stream>>>(bdv, bfv, odv, ofv, nsrc);
    scanC_kernel<<<N / 256, 256, 0, stream>>>(flag, ldv, lfv, odv, ofv,
                                              rowptr, cursor, rank, perm, N, E);
    scatter_kernel<<<(E + 255) / 256, 256, 0, stream>>>(ei, cursor, rank, colb, E);

    // x conversion + pooled sums; weight prep; folds
    cvtmean_kernel<<<2048, 256, 0, stream>>>(x, batch, deg, xh, pm, pp, N);
    xbar2_kernel<<<256, 256, 0, stream>>>(pm, pp, batch, Xbar, xsp, N);
    npos_kernel<<<64, 256, 0, stream>>>(deg, batch, nposb, N);
    wbig_kernel<<<dim3(32, 64), 256, 0, stream>>>(W1, W2, g1, g2, Wt);
    wfold_kernel<<<1024, 256, 0, stream>>>(W0, g0, Wr, Wfold);
    wufold_kernel<<<1024, 256, 0, stream>>>(W1, W2, g1, g2, Wr, Wufold);
    bfold_kernel<<<1, 256, 0, stream>>>(b1, g1, be1, b2, g2, be2, Wr, bUWr);

    // compacted V-GEMM, then fused gather-max+pool
    gemm8_kernel<<<2048, 512, 0, stream>>>(xh, Wt, perm, nsrc, Cbuf);
    edgepool_kernel<<<1024, 256, 0, stream>>>(Cbuf, rowptr, colb, batch, partial, N);
    poolreduce_kernel<<<256, 256, 0, stream>>>(partial, batch, accb, N);

    final_kernel<<<64, 256, 0, stream>>>(accb, Xbar, xsp, nposb, Wfold, Wufold,
                                         bUWr, Wr, b0, g0, be0, br, batch, out, N);
}

// Round 11
// 482.568 us; speedup vs baseline: 1.0493x; 1.0493x over previous
//
#include <hip/hip_runtime.h>
#include <stdint.h>

#define DD   1024
#define GNUM 64

typedef __attribute__((ext_vector_type(8))) short short8;
typedef __attribute__((ext_vector_type(4))) float f32x4;

__device__ __forceinline__ ushort f2bf(float f) {
    unsigned u = __float_as_uint(f);
    u += 0x7FFFu + ((u >> 16) & 1u);   // RNE
    return (ushort)(u >> 16);
}
__device__ __forceinline__ float bf2f(ushort h) {
    return __uint_as_float(((unsigned)h) << 16);
}

__device__ __forceinline__ void load_lds16(const void* g, void* l) {
    __builtin_amdgcn_global_load_lds(
        (const __attribute__((address_space(1))) unsigned*)(uintptr_t)g,
        (__attribute__((address_space(3))) unsigned*)(uint32_t)(uintptr_t)l,
        16, 0, 0);
}

__device__ __forceinline__ int lbound(const int* a, int n, int v) {
    int lo = 0, hi = n;
    while (lo < hi) { int m = (lo + hi) >> 1; if (a[m] < v) lo = m + 1; else hi = m; }
    return lo;
}

// ---------------------------------------------------------------------------
// CSR build (by dst) + src-compaction flags.
// ---------------------------------------------------------------------------
__global__ __launch_bounds__(256) void zero_kernel(int* __restrict__ p, int n) {
    int i = blockIdx.x * 256 + threadIdx.x;
    if (i < n) p[i] = 0;
}

__global__ __launch_bounds__(256) void degflag_kernel(
    const int* __restrict__ ei, int* __restrict__ deg,
    int* __restrict__ flag, int E)
{
    int e = blockIdx.x * 256 + threadIdx.x;
    if (e < E) {
        atomicAdd(&deg[ei[E + e]], 1);
        flag[ei[e]] = 1;      // benign race, same value -> deterministic
    }
}

// ---- 3-phase hierarchical dual scan (deg, flag), all-int => deterministic --
__global__ __launch_bounds__(256) void scanA_kernel(
    const int* __restrict__ deg, const int* __restrict__ flag,
    int* __restrict__ ld, int* __restrict__ lf,
    int* __restrict__ bd, int* __restrict__ bf)
{
    __shared__ int sd[256], sf[256];
    const int b = blockIdx.x, t = threadIdx.x;
    const int i = b * 256 + t;
    const int d = deg[i], f = flag[i];
    sd[t] = d; sf[t] = f;
    __syncthreads();
    for (int ofs = 1; ofs < 256; ofs <<= 1) {
        int vd = (t >= ofs) ? sd[t - ofs] : 0;
        int vf = (t >= ofs) ? sf[t - ofs] : 0;
        __syncthreads();
        sd[t] += vd; sf[t] += vf;
        __syncthreads();
    }
    ld[i] = sd[t] - d;     // exclusive
    lf[i] = sf[t] - f;
    if (t == 255) { bd[b] = sd[255]; bf[b] = sf[255]; }
}

__global__ __launch_bounds__(256) void scanB_kernel(
    const int* __restrict__ bd, const int* __restrict__ bf,
    int* __restrict__ od, int* __restrict__ of_, int* __restrict__ nsrc)
{
    __shared__ int sd[256], sf[256];
    const int t = threadIdx.x;
    const int d = bd[t], f = bf[t];
    sd[t] = d; sf[t] = f;
    __syncthreads();
    for (int ofs = 1; ofs < 256; ofs <<= 1) {
        int vd = (t >= ofs) ? sd[t - ofs] : 0;
        int vf = (t >= ofs) ? sf[t - ofs] : 0;
        __syncthreads();
        sd[t] += vd; sf[t] += vf;
        __syncthreads();
    }
    od[t] = sd[t] - d;
    of_[t] = sf[t] - f;
    if (t == 255) *nsrc = sf[255];
}

__global__ __launch_bounds__(256) void scanC_kernel(
    const int* __restrict__ flag, const int* __restrict__ ld,
    const int* __restrict__ lf, const int* __restrict__ od,
    const int* __restrict__ of_, int* __restrict__ rowptr,
    int* __restrict__ cursor, int* __restrict__ rank,
    int* __restrict__ perm, int N, int E)
{
    const int b = blockIdx.x, t = threadIdx.x;
    const int i = b * 256 + t;
    const int rd = od[b] + ld[i];
    rowptr[i] = rd;
    cursor[i] = rd;
    const int rf = of_[b] + lf[i];
    rank[i] = rf;
    if (flag[i]) perm[rf] = i;
    if (i == N - 1) rowptr[N] = E;
}

// colb stores the COMPACTED src index (rank[src])
__global__ __launch_bounds__(256) void scatter_kernel(
    const int* __restrict__ ei, int* __restrict__ cursor,
    const int* __restrict__ rank, int* __restrict__ col, int E)
{
    int e = blockIdx.x * 256 + threadIdx.x;
    if (e < E) {
        int d = ei[E + e];
        int pos = atomicAdd(&cursor[d], 1);
        col[pos] = rank[ei[e]];
    }
}

// ---------------------------------------------------------------------------
// Fused x->bf16 + per-graph partial sums (all nodes, and deg>0 nodes only).
// ---------------------------------------------------------------------------
__global__ __launch_bounds__(256) void cvtmean_kernel(
    const float* __restrict__ x, const int* __restrict__ batch,
    const int* __restrict__ deg, ushort* __restrict__ xh,
    float* __restrict__ pm, float* __restrict__ pp, int N)
{
    const int b = blockIdx.x;          // 64*32
    const int g = b >> 5, sub = b & 31;
    const int d4 = threadIdx.x * 4;

    const int glo = lbound(batch, N, g);
    const int ghi = lbound(batch, N, g + 1);
    const int len = ghi - glo;
    const int s0 = glo + (len * sub) / 32;
    const int s1 = glo + (len * (sub + 1)) / 32;

    float4 sum = make_float4(0.f, 0.f, 0.f, 0.f);
    float4 sump = make_float4(0.f, 0.f, 0.f, 0.f);
    for (int r = s0; r < s1; ++r) {
        float4 v = *(const float4*)(x + (size_t)r * 1024 + d4);
        sum.x += v.x; sum.y += v.y; sum.z += v.z; sum.w += v.w;
        if (deg[r] > 0) { sump.x += v.x; sump.y += v.y; sump.z += v.z; sump.w += v.w; }
        ushort4 h = make_ushort4(f2bf(v.x), f2bf(v.y), f2bf(v.z), f2bf(v.w));
        *(ushort4*)(xh + (size_t)r * 1024 + d4) = h;
    }
    size_t o = (size_t)(g * 32 + sub) * 1024 + d4;
    *(float4*)(pm + o) = sum;
    *(float4*)(pp + o) = sump;
}

__global__ __launch_bounds__(256) void xbar2_kernel(
    const float* __restrict__ pm, const float* __restrict__ pp,
    const int* __restrict__ batch, float* __restrict__ Xbar,
    float* __restrict__ xsp, int N)
{
    int g = blockIdx.x >> 2;
    int c = ((blockIdx.x & 3) << 8) + threadIdx.x;
    float s = 0.f, sp = 0.f;
    #pragma unroll
    for (int k = 0; k < 32; ++k) {
        s  += pm[(size_t)(g * 32 + k) * 1024 + c];
        sp += pp[(size_t)(g * 32 + k) * 1024 + c];
    }
    int cnt = lbound(batch, N, g + 1) - lbound(batch, N, g);
    if (cnt < 1) cnt = 1;
    Xbar[g * 1024 + c] = s / (float)cnt;
    xsp[g * 1024 + c] = sp;
}

__global__ __launch_bounds__(256) void npos_kernel(
    const int* __restrict__ deg, const int* __restrict__ batch,
    float* __restrict__ npos, int N)
{
    __shared__ int r[256];
    int g = blockIdx.x, t = threadIdx.x;
    int glo = lbound(batch, N, g);
    int ghi = lbound(batch, N, g + 1);
    int c = 0;
    for (int i = glo + t; i < ghi; i += 256) c += (deg[i] > 0) ? 1 : 0;
    r[t] = c;
    __syncthreads();
    for (int s = 128; s > 0; s >>= 1) {
        if (t < s) r[t] += r[t + s];
        __syncthreads();
    }
    if (t == 0) npos[g] = (float)r[0];
}

// ---------------------------------------------------------------------------
// WbigT [2048][1024] bf16: V weights only (transposed, BN scale folded).
// ---------------------------------------------------------------------------
__global__ __launch_bounds__(256) void wbig_kernel(
    const float* __restrict__ W1, const float* __restrict__ W2,
    const float* __restrict__ g1, const float* __restrict__ g2,
    ushort* __restrict__ Wt)
{
    __shared__ float tile[32][33];
    const float SF = 1.0f / sqrtf(1.0f + 1e-5f);
    int k0 = blockIdx.x * 32, c0 = blockIdx.y * 32;
    int tx = threadIdx.x & 31, ty = threadIdx.x >> 5;
    int sec = c0 >> 10;
    int cl = (c0 & 1023) + tx;
    const float* W  = sec ? W2 : W1;
    const float* gv = sec ? g2 : g1;
    float sc = gv[cl] * SF;
    #pragma unroll
    for (int j = 0; j < 4; ++j) {
        int k = k0 + ty + j * 8;
        tile[ty + j * 8][tx] = W[(size_t)(k + 1024) * 1024 + cl] * sc;
    }
    __syncthreads();
    #pragma unroll
    for (int j = 0; j < 4; ++j) {
        int cc = ty + j * 8;
        Wt[(size_t)(c0 + cc) * 1024 + k0 + tx] = f2bf(tile[tx][cc]);
    }
}

__global__ __launch_bounds__(256) void wfold_kernel(
    const float* __restrict__ W0, const float* __restrict__ g0,
    const float* __restrict__ Wr, float* __restrict__ Wfold)
{
    __shared__ float r0s[256], r1s[256];
    const float SF = 1.0f / sqrtf(1.0f + 1e-5f);
    int k = blockIdx.x, t = threadIdx.x;
    float a0 = 0.f, a1 = 0.f;
    for (int c = t; c < 1024; c += 256) {
        float w = W0[(size_t)k * 1024 + c] * (g0[c] * SF);
        a0 += w * Wr[c * 2];
        a1 += w * Wr[c * 2 + 1];
    }
    r0s[t] = a0; r1s[t] = a1;
    __syncthreads();
    for (int s = 128; s > 0; s >>= 1) {
        if (t < s) { r0s[t] += r0s[t + s]; r1s[t] += r1s[t + s]; }
        __syncthreads();
    }
    if (t == 0) { Wfold[k * 2] = r0s[0]; Wfold[k * 2 + 1] = r1s[0]; }
}

__global__ __launch_bounds__(256) void wufold_kernel(
    const float* __restrict__ W1, const float* __restrict__ W2,
    const float* __restrict__ g1, const float* __restrict__ g2,
    const float* __restrict__ Wr, float* __restrict__ Wufold)
{
    __shared__ float r0s[256], r1s[256];
    const float SF = 1.0f / sqrtf(1.0f + 1e-5f);
    int k = blockIdx.x, t = threadIdx.x;
    float a0 = 0.f, a1 = 0.f;
    for (int c = t; c < 1024; c += 256) {
        float wu = (W1[(size_t)k * 1024 + c] - W1[(size_t)(k + 1024) * 1024 + c]) * (g1[c] * SF)
                 + (W2[(size_t)k * 1024 + c] - W2[(size_t)(k + 1024) * 1024 + c]) * (g2[c] * SF);
        a0 += wu * Wr[c * 2];
        a1 += wu * Wr[c * 2 + 1];
    }
    r0s[t] = a0; r1s[t] = a1;
    __syncthreads();
    for (int s = 128; s > 0; s >>= 1) {
        if (t < s) { r0s[t] += r0s[t + s]; r1s[t] += r1s[t + s]; }
        __syncthreads();
    }
    if (t == 0) { Wufold[k * 2] = r0s[0]; Wufold[k * 2 + 1] = r1s[0]; }
}

__global__ __launch_bounds__(256) void bfold_kernel(
    const float* __restrict__ b1, const float* __restrict__ g1, const float* __restrict__ be1,
    const float* __restrict__ b2, const float* __restrict__ g2, const float* __restrict__ be2,
    const float* __restrict__ Wr, float* __restrict__ bUWr)
{
    __shared__ float r0s[256], r1s[256];
    const float SF = 1.0f / sqrtf(1.0f + 1e-5f);
    int t = threadIdx.x;
    float a0 = 0.f, a1 = 0.f;
    for (int c = t; c < 1024; c += 256) {
        float bu = b1[c] * (g1[c] * SF) + be1[c] + b2[c] * (g2[c] * SF) + be2[c];
        a0 += bu * Wr[c * 2];
        a1 += bu * Wr[c * 2 + 1];
    }
    r0s[t] = a0; r1s[t] = a1;
    __syncthreads();
    for (int s = 128; s > 0; s >>= 1) {
        if (t < s) { r0s[t] += r0s[t + s]; r1s[t] += r1s[t + s]; }
        __syncthreads();
    }
    if (t == 0) { bUWr[0] = r0s[0]; bUWr[1] = r1s[0]; }
}

// ---------------------------------------------------------------------------
// 256x256-tile 8-phase bf16 GEMM over COMPACTED src rows. (round-9 config:
// 128 KiB LDS, A/B double-buffered, boundary vmcnt(4) — counter-verified
// 255 us / MfmaUtil 41%; round-10's deeper pipeline was neutral-negative.)
// XCD-interleaved m-tiles: XCD c owns mt == c (mod 8), n fastest.
// ---------------------------------------------------------------------------
__global__ __launch_bounds__(512, 2) void gemm8_kernel(
    const ushort* __restrict__ A, const ushort* __restrict__ Bt,
    const int* __restrict__ perm, const int* __restrict__ nsrc,
    ushort* __restrict__ C)
{
    __shared__ __align__(16) ushort SM[65536];   // 128 KiB
    const int tid  = threadIdx.x;
    const int w    = tid >> 6;
    const int lane = tid & 63;
    const int wr = w >> 2;
    const int wc = w & 3;

    const int bx  = blockIdx.x;
    const int cx  = bx & 7;             // XCD chunk
    const int idx = bx >> 3;            // 0..255
    const int mt  = (idx >> 3) * 8 + cx;
    const int nt  = idx & 7;
    const int m0 = mt * 256;
    const int n0 = nt * 256;

    const int nsv = *nsrc;
    if (m0 >= nsv) return;              // whole m-tile beyond compacted rows

    const int srow = lane >> 3;
    const int csw  = ((lane & 7) ^ srow) << 3;

    const int prow = w * 8 + srow;
    int pr[4];
    #pragma unroll
    for (int z = 0; z < 4; ++z) {
        int r = m0 + z * 64 + prow;
        int p_ = perm[r];
        pr[z] = (r < nsv) ? p_ : 0;
    }

    auto stA = [&](int t, int h) {
        if (t >= 16) return;
        const int c = t & 1;
        const ushort* s0 = A + (size_t)pr[2 * h]     * 1024 + t * 64 + csw;
        const ushort* s1 = A + (size_t)pr[2 * h + 1] * 1024 + t * 64 + csw;
        ushort* d = SM + c * 16384 + h * 8192 + w * 512;
        load_lds16(s0, d);
        load_lds16(s1, d + 4096);
    };
    auto stB = [&](int t, int h) {
        if (t >= 16) return;
        const int c = t & 1;
        const ushort* s = Bt + (size_t)(n0 + h * 128 + w * 8 + srow) * 1024 + t * 64 + csw;
        ushort* d = SM + 32768 + c * 16384 + h * 8192 + w * 512;
        load_lds16(s, d);
        load_lds16(s + (size_t)64 * 1024, d + 4096);
    };

    const int cbk0 = ((lane >> 4) << 4);
    const int cbx2 = (lane & 7) << 4;
    auto rdA = [&](int c, int i, int kk) -> short8 {
        int row = i * 16 + (lane & 15);
        int cb  = (kk * 64 + cbk0) ^ cbx2;
        return *(const short8*)((const char*)SM + (c * 16384 + wr * 8192) * 2 + row * 128 + cb);
    };
    auto rdB = [&](int c, int j, int kk) -> short8 {
        int row = (wc & 1) * 64 + j * 16 + (lane & 15);
        int cb  = (kk * 64 + cbk0) ^ cbx2;
        return *(const short8*)((const char*)SM + 65536 + (c * 16384 + (wc >> 1) * 8192) * 2 + row * 128 + cb);
    };

    f32x4 acc[8][4];
    #pragma unroll
    for (int i = 0; i < 8; ++i)
        #pragma unroll
        for (int j = 0; j < 4; ++j)
            acc[i][j] = (f32x4){0.f, 0.f, 0.f, 0.f};

    short8 afr[4][2], bfr[4][2];

    stA(0, 0); stA(0, 1); stB(0, 0); stB(0, 1); stB(1, 0); stB(1, 1);
    asm volatile("s_waitcnt vmcnt(4)" ::: "memory");
    __builtin_amdgcn_s_barrier();

    for (int t = 0; t < 16; ++t) {
        const int c = t & 1;
        // P1
        #pragma unroll
        for (int i = 0; i < 4; ++i) { afr[i][0] = rdA(c, i, 0); afr[i][1] = rdA(c, i, 1); }
        #pragma unroll
        for (int j = 0; j < 2; ++j) { bfr[j][0] = rdB(c, j, 0); bfr[j][1] = rdB(c, j, 1); }
        stA(t + 1, 0);
        __builtin_amdgcn_s_barrier();
        __builtin_amdgcn_s_setprio(1);
        #pragma unroll
        for (int i = 0; i < 4; ++i)
            #pragma unroll
            for (int j = 0; j < 2; ++j) {
                acc[i][j] = __builtin_amdgcn_mfma_f32_16x16x32_bf16(bfr[j][0], afr[i][0], acc[i][j], 0, 0, 0);
                acc[i][j] = __builtin_amdgcn_mfma_f32_16x16x32_bf16(bfr[j][1], afr[i][1], acc[i][j], 0, 0, 0);
            }
        __builtin_amdgcn_s_setprio(0);
        __builtin_amdgcn_s_barrier();

        // P2
        #pragma unroll
        for (int j = 2; j < 4; ++j) { bfr[j][0] = rdB(c, j, 0); bfr[j][1] = rdB(c, j, 1); }
        stA(t + 1, 1);
        __builtin_amdgcn_s_barrier();
        __builtin_amdgcn_s_setprio(1);
        #pragma unroll
        for (int i = 0; i < 4; ++i)
            #pragma unroll
            for (int j = 2; j < 4; ++j) {
                acc[i][j] = __builtin_amdgcn_mfma_f32_16x16x32_bf16(bfr[j][0], afr[i][0], acc[i][j], 0, 0, 0);
                acc[i][j] = __builtin_amdgcn_mfma_f32_16x16x32_bf16(bfr[j][1], afr[i][1], acc[i][j], 0, 0, 0);
            }
        __builtin_amdgcn_s_setprio(0);
        __builtin_amdgcn_s_barrier();

        // P3
        #pragma unroll
        for (int i = 0; i < 4; ++i) { afr[i][0] = rdA(c, i + 4, 0); afr[i][1] = rdA(c, i + 4, 1); }
        stB(t + 2, 0);
        __builtin_amdgcn_s_barrier();
        __builtin_amdgcn_s_setprio(1);
        #pragma unroll
        for (int i = 0; i < 4; ++i)
            #pragma unroll
            for (int j = 2; j < 4; ++j) {
                acc[i + 4][j] = __builtin_amdgcn_mfma_f32_16x16x32_bf16(bfr[j][0], afr[i][0], acc[i + 4][j], 0, 0, 0);
                acc[i + 4][j] = __builtin_amdgcn_mfma_f32_16x16x32_bf16(bfr[j][1], afr[i][1], acc[i + 4][j], 0, 0, 0);
            }
        __builtin_amdgcn_s_setprio(0);
        __builtin_amdgcn_s_barrier();

        // P4
        stB(t + 2, 1);
        __builtin_amdgcn_s_barrier();
        __builtin_amdgcn_s_setprio(1);
        #pragma unroll
        for (int i = 0; i < 4; ++i)
            #pragma unroll
            for (int j = 0; j < 2; ++j) {
                acc[i + 4][j] = __builtin_amdgcn_mfma_f32_16x16x32_bf16(bfr[j][0], afr[i][0], acc[i + 4][j], 0, 0, 0);
                acc[i + 4][j] = __builtin_amdgcn_mfma_f32_16x16x32_bf16(bfr[j][1], afr[i][1], acc[i + 4][j], 0, 0, 0);
            }
        __builtin_amdgcn_s_setprio(0);
        if (t < 15) {
            if (t < 14) asm volatile("s_waitcnt vmcnt(4)" ::: "memory");
            else        asm volatile("s_waitcnt vmcnt(0)" ::: "memory");
            __builtin_amdgcn_s_barrier();
        }
    }

    // epilogue (swapped D): lane owns row ml x 4 consecutive cols nl.
    __syncthreads();
    {
        const int mls = wr * 128 + (lane & 15);
        const int nls = wc * 64 + ((lane >> 4) << 2);
        #pragma unroll
        for (int j = 0; j < 4; ++j) {
            const int nl = nls + j * 16;
            #pragma unroll
            for (int i = 0; i < 8; ++i) {
                const int ml = mls + i * 16;
                unsigned lo = (unsigned)f2bf(acc[i][j][0]) |
                              ((unsigned)f2bf(acc[i][j][1]) << 16);
                unsigned hi = (unsigned)f2bf(acc[i][j][2]) |
                              ((unsigned)f2bf(acc[i][j][3]) << 16);
                int u = (ml * 256 + nl) ^ ((ml & 15) << 2);
                *(uint2*)(SM + u) = make_uint2(lo, hi);
            }
        }
    }
    __syncthreads();
    #pragma unroll
    for (int p = 0; p < 32; ++p) {
        const int idx2 = p * 512 + tid;      // 16384 uint2 slots
        const int row = idx2 >> 6;
        const int cu  = (idx2 & 63) * 4;     // ushort offset
        int u = (row * 256 + cu) ^ ((row & 15) << 2);
        uint2 v = *(const uint2*)(SM + u);
        *(uint2*)(&C[(size_t)(m0 + row) * 2048 + n0 + cu]) = v;
    }
}

// ---------------------------------------------------------------------------
// Fused gather-max + pool partials over compacted V rows (2048 cols).
// 32 subs/graph (2048 blocks = 8/CU) to hide gather latency.
// ---------------------------------------------------------------------------
__global__ __launch_bounds__(256) void edgepool_kernel(
    const ushort* __restrict__ C, const int* __restrict__ rowptr,
    const int* __restrict__ colb, const int* __restrict__ batch,
    float* __restrict__ partial, int N)
{
    const int b = blockIdx.x;          // 64*32
    const int g = b >> 5, sub = b & 31;
    const int d8 = threadIdx.x * 8;

    const int glo = lbound(batch, N, g);
    const int ghi = lbound(batch, N, g + 1);
    const int len = ghi - glo;
    const int s0 = glo + (len * sub) / 32;
    const int s1 = glo + (len * (sub + 1)) / 32;

    float vsum[8];
    #pragma unroll
    for (int q = 0; q < 8; ++q) vsum[q] = 0.f;

    int lo = (s0 < s1) ? rowptr[s0] : 0;
    for (int node = s0; node < s1; ++node) {
        int hi = rowptr[node + 1];
        if (hi > lo) {
            float vmax[8];
            #pragma unroll
            for (int q = 0; q < 8; ++q) vmax[q] = -3.4e38f;
            for (int j = lo; j < hi; ++j) {
                int src = colb[j];
                short8 v = *(const short8*)(C + (size_t)src * 2048 + d8);
                #pragma unroll
                for (int q = 0; q < 8; ++q)
                    vmax[q] = fmaxf(vmax[q], bf2f((ushort)v[q]));
            }
            #pragma unroll
            for (int q = 0; q < 8; ++q) vsum[q] += vmax[q];
        }
        lo = hi;
    }
    float* p = partial + (size_t)(g * 32 + sub) * 2048 + d8;
    *(float4*)(p)     = make_float4(vsum[0], vsum[1], vsum[2], vsum[3]);
    *(float4*)(p + 4) = make_float4(vsum[4], vsum[5], vsum[6], vsum[7]);
}

__global__ __launch_bounds__(256) void poolreduce_kernel(
    const float* __restrict__ partial, const int* __restrict__ batch,
    float* __restrict__ acc, int N)
{
    int g = blockIdx.x >> 2;
    int c = ((blockIdx.x & 3) << 8) + threadIdx.x;
    float s = 0.f;
    #pragma unroll
    for (int k = 0; k < 32; ++k) {
        const float* p = partial + (size_t)(g * 32 + k) * 2048;
        s += p[c] + p[c + 1024];
    }
    int cnt = lbound(batch, N, g + 1) - lbound(batch, N, g);
    if (cnt < 1) cnt = 1;
    acc[g * 1024 + c] = s / (float)cnt;
}

__global__ __launch_bounds__(256) void final_kernel(
    const float* __restrict__ acc, const float* __restrict__ Xbar,
    const float* __restrict__ xsp, const float* __restrict__ npos,
    const float* __restrict__ Wfold, const float* __restrict__ Wufold,
    const float* __restrict__ bUWr, const float* __restrict__ Wr,
    const float* __restrict__ b0, const float* __restrict__ g0,
    const float* __restrict__ be0, const float* __restrict__ br,
    const int* __restrict__ batch, float* __restrict__ out, int N)
{
    __shared__ float r0[256], r1[256], r2[256], r3[256];
    const float SF = 1.0f / sqrtf(1.0f + 1e-5f);
    int g = blockIdx.x, t = threadIdx.x;
    float p0 = 0.f, p1 = 0.f, q0 = 0.f, q1 = 0.f;
    for (int c = t; c < 1024; c += 256) {
        float a = acc[g * 1024 + c] + b0[c] * (g0[c] * SF) + be0[c];
        p0 += a * Wr[c * 2];
        p1 += a * Wr[c * 2 + 1];
        float xb = Xbar[g * 1024 + c];
        p0 += xb * Wfold[c * 2];
        p1 += xb * Wfold[c * 2 + 1];
        float xs = xsp[g * 1024 + c];
        q0 += xs * Wufold[c * 2];
        q1 += xs * Wufold[c * 2 + 1];
    }
    r0[t] = p0; r1[t] = p1; r2[t] = q0; r3[t] = q1;
    __syncthreads();
    for (int s = 128; s > 0; s >>= 1) {
        if (t < s) {
            r0[t] += r0[t + s]; r1[t] += r1[t + s];
            r2[t] += r2[t + s]; r3[t] += r3[t + s];
        }
        __syncthreads();
    }
    if (t == 0) {
        int cnt = lbound(batch, N, g + 1) - lbound(batch, N, g);
        if (cnt < 1) cnt = 1;
        float ic = 1.0f / (float)cnt;
        out[g * 2 + 0] = r0[0] + (r2[0] + npos[g] * bUWr[0]) * ic + br[0];
        out[g * 2 + 1] = r1[0] + (r3[0] + npos[g] * bUWr[1]) * ic + br[1];
    }
}

extern "C" void kernel_launch(void* const* d_in, const int* in_sizes, int n_in,
                              void* d_out, int out_size, void* d_ws, size_t ws_size,
                              hipStream_t stream)
{
    const float* x   = (const float*)d_in[0];
    const int*   ei  = (const int*)d_in[1];
    const int* batch = (const int*)d_in[2];
    const float* W0  = (const float*)d_in[3];
    const float* b0  = (const float*)d_in[4];
    const float* g0  = (const float*)d_in[5];
    const float* be0 = (const float*)d_in[6];
    const float* W1  = (const float*)d_in[7];
    const float* b1  = (const float*)d_in[8];
    const float* g1  = (const float*)d_in[9];
    const float* be1 = (const float*)d_in[10];
    const float* W2  = (const float*)d_in[11];
    const float* b2  = (const float*)d_in[12];
    const float* g2  = (const float*)d_in[13];
    const float* be2 = (const float*)d_in[14];
    const float* Wr  = (const float*)d_in[15];
    const float* br  = (const float*)d_in[16];
    float* out = (float*)d_out;

    const int N = in_sizes[2];       // 65536
    const int E = in_sizes[1] / 2;   // 131072

    char* ws = (char*)d_ws;
    size_t off = 0;
    auto alloc = [&](size_t bytes) -> void* {
        off = (off + 255) & ~(size_t)255;
        void* p = ws + off;
        off += bytes;
        return p;
    };
    ushort*   xh      = (ushort*)alloc((size_t)N * 1024 * 2);
    ushort*   Wt      = (ushort*)alloc((size_t)2048 * 1024 * 2);
    float*    Xbar    = (float*)alloc(64 * 1024 * 4);
    float*    xsp     = (float*)alloc(64 * 1024 * 4);
    float*    accb    = (float*)alloc(64 * 1024 * 4);
    float*    Wfold   = (float*)alloc(1024 * 2 * 4);
    float*    Wufold  = (float*)alloc(1024 * 2 * 4);
    float*    bUWr    = (float*)alloc(256);
    float*    nposb   = (float*)alloc(64 * 4);
    ushort*   Cbuf    = (ushort*)alloc((size_t)N * 2048 * 2);
    float*    partial = (float*)alloc((size_t)2048 * 2048 * 4);
    float*    pm      = (float*)alloc((size_t)2048 * 1024 * 4);
    float*    pp      = (float*)alloc((size_t)2048 * 1024 * 4);
    int*      deg     = (int*)alloc((size_t)N * 4);
    int*      flag    = (int*)alloc((size_t)N * 4);
    int*      rowptr  = (int*)alloc(((size_t)N + 1) * 4);
    int*      cursor  = (int*)alloc((size_t)N * 4);
    int*      rank    = (int*)alloc((size_t)N * 4);
    int*      perm    = (int*)alloc((size_t)N * 4);
    int*      nsrc    = (int*)alloc(256);
    int*      colb    = (int*)alloc((size_t)E * 4);
    int*      ldv     = (int*)alloc((size_t)N * 4);
    int*      lfv     = (int*)alloc((size_t)N * 4);
    int*      bdv     = (int*)alloc(256 * 4);
    int*      bfv     = (int*)alloc(256 * 4);
    int*      odv     = (int*)alloc(256 * 4);
    int*      ofv     = (int*)alloc(256 * 4);
    (void)ws_size; (void)n_in; (void)out_size;

    // CSR + compaction (hierarchical 3-phase dual scan)
    zero_kernel<<<(N + 255) / 256, 256, 0, stream>>>(deg, N);
    zero_kernel<<<(N + 255) / 256, 256, 0, stream>>>(flag, N);
    degflag_kernel<<<(E + 255) / 256, 256, 0, stream>>>(ei, deg, flag, E);
    scanA_kernel<<<N / 256, 256, 0, stream>>>(deg, flag, ldv, lfv, bdv, bfv);
    scanB_kernel<<<1, 256, 0, stream>>>(bdv, bfv, odv, ofv, nsrc);
    scanC_kernel<<<N / 256, 256, 0, stream>>>(flag, ldv, lfv, odv, ofv,
                                              rowptr, cursor, rank, perm, N, E);
    scatter_kernel<<<(E + 255) / 256, 256, 0, stream>>>(ei, cursor, rank, colb, E);

    // x conversion + pooled sums; weight prep; folds
    cvtmean_kernel<<<2048, 256, 0, stream>>>(x, batch, deg, xh, pm, pp, N);
    xbar2_kernel<<<256, 256, 0, stream>>>(pm, pp, batch, Xbar, xsp, N);
    npos_kernel<<<64, 256, 0, stream>>>(deg, batch, nposb, N);
    wbig_kernel<<<dim3(32, 64), 256, 0, stream>>>(W1, W2, g1, g2, Wt);
    wfold_kernel<<<1024, 256, 0, stream>>>(W0, g0, Wr, Wfold);
    wufold_kernel<<<1024, 256, 0, stream>>>(W1, W2, g1, g2, Wr, Wufold);
    bfold_kernel<<<1, 256, 0, stream>>>(b1, g1, be1, b2, g2, be2, Wr, bUWr);

    // compacted V-GEMM, then fused gather-max+pool
    gemm8_kernel<<<2048, 512, 0, stream>>>(xh, Wt, perm, nsrc, Cbuf);
    edgepool_kernel<<<2048, 256, 0, stream>>>(Cbuf, rowptr, colb, batch, partial, N);
    poolreduce_kernel<<<256, 256, 0, stream>>>(partial, batch, accb, N);

    final_kernel<<<64, 256, 0, stream>>>(accb, Xbar, xsp, nposb, Wfold, Wufold,
                                         bUWr, Wr, b0, g0, be0, br, batch, out, N);
}